// Round 16
// baseline (481.616 us; speedup 1.0000x reference)
//
#include <hip/hip_runtime.h>
#include <cstddef>

typedef unsigned short ushort_t;
typedef unsigned int uint32;

typedef __bf16   bf16x8 __attribute__((ext_vector_type(8)));
typedef __bf16   bf16x2 __attribute__((ext_vector_type(2)));
typedef __bf16   bf16x4 __attribute__((ext_vector_type(4)));
typedef float    f32x16 __attribute__((ext_vector_type(16)));
typedef float    f32x4  __attribute__((ext_vector_type(4)));
typedef ushort_t u16x8  __attribute__((ext_vector_type(8)));
typedef ushort_t u16x4  __attribute__((ext_vector_type(4)));
typedef uint32   u32x4  __attribute__((ext_vector_type(4)));
typedef uint32   u32x2  __attribute__((ext_vector_type(2)));

__device__ __forceinline__ ushort_t f2b(float f) {
  uint32 u = __builtin_bit_cast(uint32, f);
  u += 0x7fff + ((u >> 16) & 1);           // RNE
  return (ushort_t)(u >> 16);
}

__device__ __forceinline__ f32x16 mfma32(bf16x8 a, bf16x8 b, f32x16 c) {
  return __builtin_amdgcn_mfma_f32_32x32x16_bf16(a, b, c, 0, 0, 0);
}

__device__ __forceinline__ void gload_lds16(const void* g, void* l) {
  __builtin_amdgcn_global_load_lds((const __attribute__((address_space(1))) void*)g,
                                   (__attribute__((address_space(3))) void*)l, 16, 0, 0);
}

// ---------------- Fused prep: RoPE table + x cvt + 3 weight transposes ---------
__launch_bounds__(256)
__global__ void k_prep(const float* __restrict__ x, ushort_t* __restrict__ x_c, int nCvt,
                       const float* __restrict__ Wq, ushort_t* __restrict__ WqT,
                       const float* __restrict__ Wkv, ushort_t* __restrict__ WkvT,
                       const float* __restrict__ Wo, ushort_t* __restrict__ WoT,
                       float* __restrict__ cosT, float* __restrict__ sinT) {
  __shared__ __align__(16) ushort_t tile[64][72];
  const int tid = threadIdx.x;
  int bid = blockIdx.x;
  if (bid < 512) {  // rope table
    int idx = bid * 256 + tid;   // 4096*32 = 131072
    int t = idx >> 5, j = idx & 31;
    float invf = __expf(-(float)j * (9.210340371976184f / 32.0f));  // 10000^(-j/32)
    float ang = (float)t * invf;
    cosT[idx] = cosf(ang);
    sinT[idx] = sinf(ang);
    return;
  }
  bid -= 512;
  if (bid < nCvt) {  // x convert
    size_t i = ((size_t)bid * 256 + tid) * 8;
    f32x4 a = *(const f32x4*)(x + i);
    f32x4 b = *(const f32x4*)(x + i + 4);
    u16x8 v = {f2b(a[0]), f2b(a[1]), f2b(a[2]), f2b(a[3]),
               f2b(b[0]), f2b(b[1]), f2b(b[2]), f2b(b[3])};
    *(u16x8*)(x_c + i) = v;
    return;
  }
  bid -= nCvt;
  const float* W;
  ushort_t* Wt;
  int N;
  if (bid < 1024)      { W = Wq;  Wt = WqT;  N = 2048; }
  else if (bid < 1536) { W = Wkv; Wt = WkvT; N = 1024; bid -= 1024; }
  else                 { W = Wo;  Wt = WoT;  N = 2048; bid -= 1536; }
  const int K = 2048;
  int nbx = N >> 6;
  int bx = bid % nbx, by = bid / nbx;
  int r0 = by << 6, c0 = bx << 6;
#pragma unroll
  for (int p = 0; p < 2; p++) {
    int id = p * 256 + tid;
    int r = id >> 3, cs = id & 7;
    const float* src = W + (size_t)(r0 + r) * N + c0 + cs * 8;
    f32x4 a = *(const f32x4*)(src);
    f32x4 b = *(const f32x4*)(src + 4);
    u16x8 v = {f2b(a[0]), f2b(a[1]), f2b(a[2]), f2b(a[3]),
               f2b(b[0]), f2b(b[1]), f2b(b[2]), f2b(b[3])};
    *(u16x8*)&tile[r][cs * 8] = v;
  }
  __syncthreads();
#pragma unroll
  for (int p = 0; p < 2; p++) {
    int id = p * 256 + tid;
    int oc = id >> 3, ocs = id & 7;
    u16x8 v;
#pragma unroll
    for (int j = 0; j < 8; j++) v[j] = tile[ocs * 8 + j][oc];
    *(u16x8*)(Wt + (size_t)(c0 + oc) * K + r0 + ocs * 8) = v;
  }
}

// ---------------- Merged Q+KV GEMM, 256x256 tile, 8 waves (512 thr) ----------
// Round 16: tile 128x128 -> 256x256 halves both A- and B-panel re-read factors
// (FETCH was 117MB vs ~44MB unique at 2.7x re-fetch). All components proven:
// same 32x32x16 fragment algebra, same linear gload_lds staging (8 waves x 32
// rows), same 2-barrier K-loop. Wave grid 4Mx2N, per-wave 64x128 (acc[2][4]).
// V stored kappa-permuted; Q pre-scaled by 0.125*log2(e). Swizzle reverted
// (r15: conflicts 3x down, time +5% — off critical path at 2-phase).
__launch_bounds__(512)
__global__ void k_gemm_qkv(const ushort_t* __restrict__ A,
                           const ushort_t* __restrict__ BtQ,
                           const ushort_t* __restrict__ BtKV, int M,
                           ushort_t* __restrict__ qout, ushort_t* __restrict__ kout,
                           ushort_t* __restrict__ vout,
                           const float* __restrict__ cosT,
                           const float* __restrict__ sinT) {
  __shared__ __align__(16) ushort_t lds[2][2][256 * 32];  // [buf][A/B][row*32] 64KB
  const int tid = threadIdx.x;
  const int wave = tid >> 6, lane = tid & 63;
  const int l31 = lane & 31, hf = lane >> 5;
  const int K = 2048;
  // XCD-chunked bijective remap (grid = (M/256)*12 = 384, % 8 == 0)
  const int bid = (int)blockIdx.x;
  const int blk = (bid & 7) * (int)(gridDim.x >> 3) + (bid >> 3);
  const int nQ = (M >> 8) << 3;         // 256 Q blocks
  const bool isQ = blk < nQ;
  int sub = isQ ? blk : blk - nQ;
  const int nTn = isQ ? 8 : 4;          // 256-col tiles
  const ushort_t* Bt = isQ ? BtQ : BtKV;
  const int st = sub >> 4, si = sub & 15;
  const int nStc = nTn >> 2;
  const int stm = st / nStc, stn = st % nStc;
  const int bm = stm * 4 + (si >> 2), bn = stn * 4 + (si & 3);
  const int row0 = bm << 8, col0 = bn << 8;

  f32x16 acc[2][4] = {};

  auto stage = [&](int buf, int k0) {
#pragma unroll
    for (int side = 0; side < 2; side++) {
      const ushort_t* src = side ? Bt : A;
      int r0g = side ? col0 : row0;
#pragma unroll
      for (int i = 0; i < 2; i++) {
        int rl = wave * 32 + i * 16 + (lane >> 2);   // 8 waves cover 256 rows
        int cs = lane & 3;
        const ushort_t* gp = src + (size_t)(r0g + rl) * K + k0 + cs * 8;
        ushort_t* lp = &lds[buf][side][(wave * 32 + i * 16) * 32];
        gload_lds16(gp, lp);
      }
    }
  };

  stage(0, 0);
  __syncthreads();

  const int wm = wave >> 1, wn = wave & 1;   // 4M x 2N
  const int nk = K >> 5;
  for (int kt = 0; kt < nk; kt++) {
    const int buf = kt & 1;
    if (kt + 1 < nk) stage(buf ^ 1, (kt + 1) << 5);
    const ushort_t* la = &lds[buf][0][0];
    const ushort_t* lb = &lds[buf][1][0];
#pragma unroll
    for (int ks = 0; ks < 2; ks++) {
      const int kc = ks * 2 + hf;
      bf16x8 af[2], bg[4];
#pragma unroll
      for (int mi = 0; mi < 2; mi++) {
        int r = wm * 64 + mi * 32 + l31;
        af[mi] = *(const bf16x8*)(la + r * 32 + kc * 8);
      }
#pragma unroll
      for (int ni = 0; ni < 4; ni++) {
        int r = wn * 128 + ni * 32 + l31;
        bg[ni] = *(const bf16x8*)(lb + r * 32 + kc * 8);
      }
#pragma unroll
      for (int mi = 0; mi < 2; mi++)
#pragma unroll
        for (int ni = 0; ni < 4; ni++)
          acc[mi][ni] = mfma32(af[mi], bg[ni], acc[mi][ni]);
    }
    __syncthreads();
  }

  // ---- epilogues (no barriers inside; branch is block-uniform) ----
  if (isQ) {  // q + RoPE, pre-scaled; wave col-span 128 = 2 heads, pair (2h,2h+1)
    const float SC = 0.18033688011112042f;
#pragma unroll
    for (int mi = 0; mi < 2; mi++)
#pragma unroll
      for (int h = 0; h < 2; h++) {
        int cg = col0 + wn * 128 + h * 64 + l31;
#pragma unroll
        for (int r = 0; r < 16; r++) {
          int rg = row0 + wm * 64 + mi * 32 + (r & 3) + 8 * (r >> 2) + 4 * hf;
          int t = rg & 4095;
          float c = cosT[t * 32 + l31];
          float s = sinT[t * 32 + l31];
          float lo = acc[mi][2 * h][r], hi = acc[mi][2 * h + 1][r];
          qout[(size_t)rg * 2048 + cg]      = f2b((lo * c - hi * s) * SC);
          qout[(size_t)rg * 2048 + cg + 32] = f2b((hi * c + lo * s) * SC);
        }
      }
  } else {
    int cb = col0 + wn * 128;   // 128-aligned; never straddles the 512 boundary
    if (cb < 512) {  // K half: RoPE, store [(b*8+g)][t][64]
#pragma unroll
      for (int mi = 0; mi < 2; mi++)
#pragma unroll
        for (int h = 0; h < 2; h++) {
          int g = (cb + h * 64) >> 6;
#pragma unroll
          for (int r = 0; r < 16; r++) {
            int rg = row0 + wm * 64 + mi * 32 + (r & 3) + 8 * (r >> 2) + 4 * hf;
            int t = rg & 4095, b = rg >> 12;
            float c = cosT[t * 32 + l31];
            float s = sinT[t * 32 + l31];
            float lo = acc[mi][2 * h][r], hi = acc[mi][2 * h + 1][r];
            size_t base = ((size_t)(b * 8 + g) * 4096 + t) * 64;
            kout[base + l31]      = f2b(lo * c - hi * s);
            kout[base + l31 + 32] = f2b(hi * c + lo * s);
          }
        }
    } else {  // V half: [(b*8+g)][kt][64 d][32 keys], key index kappa-permuted
#pragma unroll
      for (int mi = 0; mi < 2; mi++)
#pragma unroll
        for (int ni = 0; ni < 4; ni++) {
          int vd = cb + ni * 32 + l31 - 512;
          int g = vd >> 6, d = vd & 63;
#pragma unroll
          for (int g2 = 0; g2 < 4; g2++) {
            int rg = row0 + wm * 64 + mi * 32 + 8 * g2 + 4 * hf;
            int b = rg >> 12, tl = rg & 4095;
            u16x4 pk = {f2b(acc[mi][ni][g2 * 4 + 0]), f2b(acc[mi][ni][g2 * 4 + 1]),
                        f2b(acc[mi][ni][g2 * 4 + 2]), f2b(acc[mi][ni][g2 * 4 + 3])};
            size_t base = (((size_t)(b * 8 + g) * 128 + (tl >> 5)) * 64 + d) * 32;
            int vtl = 16 * (g2 >> 1) + 8 * hf + 4 * (g2 & 1);
            *(u16x4*)(vout + base + vtl) = pk;
          }
        }
    }
  }
}

// ---------------- Final projection GEMM, 256x256 tile, 8 waves ----------------
__launch_bounds__(512)
__global__ void k_gemm_o(const ushort_t* __restrict__ A, const ushort_t* __restrict__ Bt,
                         int M, float* __restrict__ outf) {
  __shared__ __align__(16) ushort_t lds[2][2][256 * 32];
  const int tid = threadIdx.x;
  const int wave = tid >> 6, lane = tid & 63;
  const int l31 = lane & 31, hf = lane >> 5;
  const int K = 2048, N = 2048, nTn = 8;
  const int bid = (int)blockIdx.x;
  const int blk = (bid & 7) * (int)(gridDim.x >> 3) + (bid >> 3);
  const int st = blk >> 4, si = blk & 15;
  const int nStc = nTn >> 2;
  const int stm = st / nStc, stn = st % nStc;
  const int bm = stm * 4 + (si >> 2), bn = stn * 4 + (si & 3);
  const int row0 = bm << 8, col0 = bn << 8;

  f32x16 acc[2][4] = {};

  auto stage = [&](int buf, int k0) {
#pragma unroll
    for (int side = 0; side < 2; side++) {
      const ushort_t* src = side ? Bt : A;
      int r0g = side ? col0 : row0;
#pragma unroll
      for (int i = 0; i < 2; i++) {
        int rl = wave * 32 + i * 16 + (lane >> 2);
        int cs = lane & 3;
        const ushort_t* gp = src + (size_t)(r0g + rl) * K + k0 + cs * 8;
        ushort_t* lp = &lds[buf][side][(wave * 32 + i * 16) * 32];
        gload_lds16(gp, lp);
      }
    }
  };

  stage(0, 0);
  __syncthreads();

  const int wm = wave >> 1, wn = wave & 1;
  const int nk = K >> 5;
  for (int kt = 0; kt < nk; kt++) {
    const int buf = kt & 1;
    if (kt + 1 < nk) stage(buf ^ 1, (kt + 1) << 5);
    const ushort_t* la = &lds[buf][0][0];
    const ushort_t* lb = &lds[buf][1][0];
#pragma unroll
    for (int ks = 0; ks < 2; ks++) {
      const int kc = ks * 2 + hf;
      bf16x8 af[2], bg[4];
#pragma unroll
      for (int mi = 0; mi < 2; mi++) {
        int r = wm * 64 + mi * 32 + l31;
        af[mi] = *(const bf16x8*)(la + r * 32 + kc * 8);
      }
#pragma unroll
      for (int ni = 0; ni < 4; ni++) {
        int r = wn * 128 + ni * 32 + l31;
        bg[ni] = *(const bf16x8*)(lb + r * 32 + kc * 8);
      }
#pragma unroll
      for (int mi = 0; mi < 2; mi++)
#pragma unroll
        for (int ni = 0; ni < 4; ni++)
          acc[mi][ni] = mfma32(af[mi], bg[ni], acc[mi][ni]);
    }
    __syncthreads();
  }

#pragma unroll
  for (int mi = 0; mi < 2; mi++)
#pragma unroll
    for (int ni = 0; ni < 4; ni++) {
      int cg = col0 + wn * 128 + ni * 32 + l31;
#pragma unroll
      for (int r = 0; r < 16; r++) {
        int rg = row0 + wm * 64 + mi * 32 + (r & 3) + 8 * (r >> 2) + 4 * hf;
        outf[(size_t)rg * N + cg] = acc[mi][ni][r];
      }
    }
}

// ---------------- Flash attention, sliding window, GQA ----------------
// Block-cooperative LDS staging. permlane32_swap BANNED (rounds 1&6). Fixed-m
// softmax with m folded away (Q pre-scaled by 0.125*log2(e): p = exp2(sa)
// directly; o/l scale-invariant; masked -1e30 -> 0 exactly). kappa-permuted V
// keeps PV exchange-free. KVBLK=64: two 32-key sub-tiles per loop iteration.
// In-place output over its own q block. (Identical to round 14.)
__launch_bounds__(256)
__global__ void k_attn(ushort_t* __restrict__ q, const ushort_t* __restrict__ kk,
                       const ushort_t* __restrict__ vT) {
  __shared__ __align__(16) ushort_t Kl[2][64][68];   // [buf][j*32+key][64 d +4 pad]
  __shared__ __align__(16) ushort_t Vl[2][128][36];  // [buf][j*64+d][32 keys +4 pad]
  const int tid = threadIdx.x;
  const int wave = tid >> 6, lane = tid & 63;
  const int l31 = lane & 31, hf = lane >> 5;
  // T1: XCD-chunked bijective remap (gridDim.x % 8 == 0 holds: 2048 blocks)
  const int chunk = gridDim.x >> 3;
  const int blk = ((int)blockIdx.x & 7) * chunk + ((int)blockIdx.x >> 3);
  const int bh = blk >> 5, qt4 = 31 - (blk & 31);   // long blocks first
  const int b = bh >> 5, hd = bh & 31;
  const int g = hd >> 2;
  const int qt = qt4 * 4 + wave;
  const int t0 = qt << 5;
  const float NEG = -1e30f;

  const ushort_t* qp = q + ((size_t)(b * 4096 + t0 + l31)) * 2048 + hd * 64 + hf * 8;
  bf16x8 qf[4];
#pragma unroll
  for (int ks = 0; ks < 4; ks++) qf[ks] = *(const bf16x8*)(qp + ks * 16);

  const ushort_t* kg = kk + (size_t)(b * 8 + g) * 4096 * 64;       // [t][64]
  const ushort_t* vg = vT + (size_t)(b * 8 + g) * 128 * 64 * 32;   // [kt][64][32]

  f32x16 o[2] = {};
  float l_i = 0.f;   // per-lane partial; cross-half reduced once at the end

  // common kt range for the whole block; pair-aligned (KTmax is always odd)
  const int KT0 = (qt4 >= 8) ? ((qt4 * 128 - 1023) >> 5) : 0;
  const int KT0e = KT0 & ~1;
  const int KTmax = qt4 * 4 + 3;

  // staging roles: K = 32 rows x 8 x 16B chunks; V = 64 rows x 4 x 16B chunks
  const int krow = tid >> 3, kchk = tid & 7;
  const int vrow = tid >> 2, vchk = tid & 3;

  // prologue: stage pair (KT0e, KT0e+1) into buf 0
#pragma unroll
  for (int j = 0; j < 2; j++) {
    u32x4 kv = *(const u32x4*)(kg + ((size_t)((KT0e + j) << 5) + krow) * 64 + kchk * 8);
    u32x4 vv = *(const u32x4*)(vg + (size_t)(KT0e + j) * 2048 + vrow * 32 + vchk * 8);
    *(u32x2*)&Kl[0][j * 32 + krow][kchk * 8]     = (u32x2){kv[0], kv[1]};
    *(u32x2*)&Kl[0][j * 32 + krow][kchk * 8 + 4] = (u32x2){kv[2], kv[3]};
    *(u32x2*)&Vl[0][j * 64 + vrow][vchk * 8]     = (u32x2){vv[0], vv[1]};
    *(u32x2*)&Vl[0][j * 64 + vrow][vchk * 8 + 4] = (u32x2){vv[2], vv[3]};
  }
  __syncthreads();

  for (int kt = KT0e; kt <= KTmax; kt += 2) {
    const int buf = ((kt - KT0e) >> 1) & 1;
    const bool more = (kt + 2 <= KTmax);

    // issue next-pair global loads early (latency hides under compute)
    u32x4 kv[2], vv[2];
    if (more) {
#pragma unroll
      for (int j = 0; j < 2; j++) {
        kv[j] = *(const u32x4*)(kg + ((size_t)((kt + 2 + j) << 5) + krow) * 64 + kchk * 8);
        vv[j] = *(const u32x4*)(vg + (size_t)(kt + 2 + j) * 2048 + vrow * 32 + vchk * 8);
      }
    }

#pragma unroll
    for (int j = 0; j < 2; j++) {
      const int ktj = kt + j;
      const int kb = ktj << 5;
      // dead-tile skip: fully masked for this wave (future, or left of window)
      const bool live = (ktj <= qt) && (kb > t0 - 1055);
      if (live) {
        // K fragments from LDS (8B-aligned b64 pairs, 2-way banks = free)
        bf16x8 kf[4];
#pragma unroll
        for (int ks = 0; ks < 4; ks++) {
          u32x2 a0 = *(const u32x2*)&Kl[buf][j * 32 + l31][hf * 8 + ks * 16];
          u32x2 a1 = *(const u32x2*)&Kl[buf][j * 32 + l31][hf * 8 + ks * 16 + 4];
          u32x4 w = {a0[0], a0[1], a1[0], a1[1]};
          kf[ks] = __builtin_bit_cast(bf16x8, w);
        }
        f32x16 sa = {};
        __builtin_amdgcn_s_setprio(1);
#pragma unroll
        for (int ks = 0; ks < 4; ks++) sa = mfma32(kf[ks], qf[ks], sa);
        __builtin_amdgcn_s_setprio(0);

        // V fragments from LDS (kappa-permuted columns)
        bf16x8 vf[2][2];
#pragma unroll
        for (int ks = 0; ks < 2; ks++)
#pragma unroll
          for (int mi = 0; mi < 2; mi++) {
            u32x2 a0 = *(const u32x2*)&Vl[buf][j * 64 + mi * 32 + l31][hf * 8 + ks * 16];
            u32x2 a1 = *(const u32x2*)&Vl[buf][j * 64 + mi * 32 + l31][hf * 8 + ks * 16 + 4];
            u32x4 w = {a0[0], a0[1], a1[0], a1[1]};
            vf[ks][mi] = __builtin_bit_cast(bf16x8, w);
          }

        // masking: diagonal tile (ktj == qt) and window left edge
        const bool need_mask = (ktj == qt) || (kb < t0 - 992);
        if (need_mask) {
          int base = (t0 + l31) - kb - 4 * hf;  // allowed iff 0 <= base - off < 1024
#pragma unroll
          for (int r = 0; r < 16; r++) {
            int off = (r & 3) + 8 * (r >> 2);
            sa[r] = ((unsigned)(base - off) < 1024u) ? sa[r] : NEG;
          }
        }
        // p = exp2(sa) directly (Q pre-scaled); masked -> exactly 0
        float p[16];
#pragma unroll
        for (int r = 0; r < 16; r++)
          p[r] = __builtin_amdgcn_exp2f(sa[r]);
        l_i += (((p[0] + p[1]) + (p[2] + p[3])) + ((p[4] + p[5]) + (p[6] + p[7]))) +
               (((p[8] + p[9]) + (p[10] + p[11])) + ((p[12] + p[13]) + (p[14] + p[15])));

        // pack P to bf16 pairs; feed PV directly (V columns kappa-permuted)
        uint32 u[8];
#pragma unroll
        for (int i = 0; i < 8; i++) {
          bf16x2 t2 = {(__bf16)p[2 * i], (__bf16)p[2 * i + 1]};
          u[i] = __builtin_bit_cast(uint32, t2);
        }

#pragma unroll
        for (int ks = 0; ks < 2; ks++) {
          u32x4 fr = {u[4 * ks + 0], u[4 * ks + 1], u[4 * ks + 2], u[4 * ks + 3]};
          bf16x8 pf = __builtin_bit_cast(bf16x8, fr);
          __builtin_amdgcn_s_setprio(1);
          o[0] = mfma32(vf[ks][0], pf, o[0]);
          o[1] = mfma32(vf[ks][1], pf, o[1]);
          __builtin_amdgcn_s_setprio(0);
        }
      }
    }

    // write next pair into the other buffer (vmcnt via data dep), then sync
    if (more) {
#pragma unroll
      for (int j = 0; j < 2; j++) {
        *(u32x2*)&Kl[buf ^ 1][j * 32 + krow][kchk * 8]     = (u32x2){kv[j][0], kv[j][1]};
        *(u32x2*)&Kl[buf ^ 1][j * 32 + krow][kchk * 8 + 4] = (u32x2){kv[j][2], kv[j][3]};
        *(u32x2*)&Vl[buf ^ 1][j * 64 + vrow][vchk * 8]     = (u32x2){vv[j][0], vv[j][1]};
        *(u32x2*)&Vl[buf ^ 1][j * 64 + vrow][vchk * 8 + 4] = (u32x2){vv[j][2], vv[j][3]};
      }
    }
    __syncthreads();
  }

  // single cross-half reduce of l (sum is associative across tiles/halves)
  l_i += __shfl_xor(l_i, 32, 64);
  float inv_l = 1.0f / fmaxf(l_i, 1e-30f);
  ushort_t* op = q + ((size_t)(b * 4096 + t0 + l31)) * 2048 + hd * 64;  // in-place
#pragma unroll
  for (int mi = 0; mi < 2; mi++)
#pragma unroll
    for (int g2 = 0; g2 < 4; g2++) {
      int d0 = mi * 32 + 8 * g2 + 4 * hf;
      bf16x4 pk = {(__bf16)(o[mi][g2 * 4 + 0] * inv_l), (__bf16)(o[mi][g2 * 4 + 1] * inv_l),
                   (__bf16)(o[mi][g2 * 4 + 2] * inv_l), (__bf16)(o[mi][g2 * 4 + 3] * inv_l)};
      *(bf16x4*)(op + d0) = pk;
    }
}

extern "C" void kernel_launch(void* const* d_in, const int* in_sizes, int n_in,
                              void* d_out, int out_size, void* d_ws, size_t ws_size,
                              hipStream_t stream) {
  const float* x   = (const float*)d_in[0];   // fp32 inputs per reference dtypes
  const float* Wq  = (const float*)d_in[1];
  const float* Wkv = (const float*)d_in[2];
  const float* Wo  = (const float*)d_in[3];
  float* outp = (float*)d_out;                // fp32 output per reference dtype

  const int BT = in_sizes[0] / 2048;  // 8192
  const int Bb = BT / 4096;           // 2

  // --- Scratch plan: d_out is 64 MiB fp32; its first 61 MiB host all scratch
  // that is dead before the final GEMM fully overwrites d_out. ws = 40 MiB.
  //   d_out: x_c[0,32M) WqT[32M,40M) WkvT[40M,44M) kbuf[44M,52M)
  //          vbuf[52M,60M) cosT[60M,60.5M) sinT[60.5M,61M)
  //   ws:    qbuf[0,32M) (attn writes in-place)  WoT[32M,40M)
  char* ob = (char*)d_out;
  const size_t MB = 1024 * 1024;
  ushort_t* x_c  = (ushort_t*)(ob);
  ushort_t* WqT  = (ushort_t*)(ob + 32 * MB);
  ushort_t* WkvT = (ushort_t*)(ob + 40 * MB);
  ushort_t* kbuf = (ushort_t*)(ob + 44 * MB);
  ushort_t* vbuf = (ushort_t*)(ob + 52 * MB);
  float*    cosT = (float*)   (ob + 60 * MB);
  float*    sinT = (float*)   (ob + 60 * MB + 512 * 1024);

  char* ws = (char*)d_ws;
  ushort_t* qbuf = (ushort_t*)(ws);
  ushort_t* WoT  = (ushort_t*)(ws + 32 * MB);

  const int nCvt = BT;  // BT*2048/(256*8)
  k_prep<<<512 + nCvt + 2560, 256, 0, stream>>>(x, x_c, nCvt, Wq, WqT, Wkv, WkvT,
                                                Wo, WoT, cosT, sinT);

  k_gemm_qkv<<<(BT / 256) * 12, 512, 0, stream>>>(
      x_c, WqT, WkvT, BT, qbuf, kbuf, vbuf, cosT, sinT);

  k_attn<<<Bb * 32 * 32, 256, 0, stream>>>(qbuf, kbuf, vbuf);

  k_gemm_o<<<(BT / 256) * 8, 512, 0, stream>>>(qbuf, WoT, BT, outp);
}

// Round 17
// 454.508 us; speedup vs baseline: 1.0596x; 1.0596x over previous
//
#include <hip/hip_runtime.h>
#include <cstddef>

typedef unsigned short ushort_t;
typedef unsigned int uint32;

typedef __bf16   bf16x8 __attribute__((ext_vector_type(8)));
typedef __bf16   bf16x2 __attribute__((ext_vector_type(2)));
typedef __bf16   bf16x4 __attribute__((ext_vector_type(4)));
typedef float    f32x16 __attribute__((ext_vector_type(16)));
typedef float    f32x4  __attribute__((ext_vector_type(4)));
typedef ushort_t u16x8  __attribute__((ext_vector_type(8)));
typedef ushort_t u16x4  __attribute__((ext_vector_type(4)));
typedef uint32   u32x4  __attribute__((ext_vector_type(4)));
typedef uint32   u32x2  __attribute__((ext_vector_type(2)));

__device__ __forceinline__ ushort_t f2b(float f) {
  uint32 u = __builtin_bit_cast(uint32, f);
  u += 0x7fff + ((u >> 16) & 1);           // RNE
  return (ushort_t)(u >> 16);
}

__device__ __forceinline__ f32x16 mfma32(bf16x8 a, bf16x8 b, f32x16 c) {
  return __builtin_amdgcn_mfma_f32_32x32x16_bf16(a, b, c, 0, 0, 0);
}

__device__ __forceinline__ void gload_lds16(const void* g, void* l) {
  __builtin_amdgcn_global_load_lds((const __attribute__((address_space(1))) void*)g,
                                   (__attribute__((address_space(3))) void*)l, 16, 0, 0);
}

// ---------------- Fused prep: RoPE table + x cvt + 3 weight transposes ---------
__launch_bounds__(256)
__global__ void k_prep(const float* __restrict__ x, ushort_t* __restrict__ x_c, int nCvt,
                       const float* __restrict__ Wq, ushort_t* __restrict__ WqT,
                       const float* __restrict__ Wkv, ushort_t* __restrict__ WkvT,
                       const float* __restrict__ Wo, ushort_t* __restrict__ WoT,
                       float* __restrict__ cosT, float* __restrict__ sinT) {
  __shared__ __align__(16) ushort_t tile[64][72];
  const int tid = threadIdx.x;
  int bid = blockIdx.x;
  if (bid < 512) {  // rope table
    int idx = bid * 256 + tid;   // 4096*32 = 131072
    int t = idx >> 5, j = idx & 31;
    float invf = __expf(-(float)j * (9.210340371976184f / 32.0f));  // 10000^(-j/32)
    float ang = (float)t * invf;
    cosT[idx] = cosf(ang);
    sinT[idx] = sinf(ang);
    return;
  }
  bid -= 512;
  if (bid < nCvt) {  // x convert
    size_t i = ((size_t)bid * 256 + tid) * 8;
    f32x4 a = *(const f32x4*)(x + i);
    f32x4 b = *(const f32x4*)(x + i + 4);
    u16x8 v = {f2b(a[0]), f2b(a[1]), f2b(a[2]), f2b(a[3]),
               f2b(b[0]), f2b(b[1]), f2b(b[2]), f2b(b[3])};
    *(u16x8*)(x_c + i) = v;
    return;
  }
  bid -= nCvt;
  const float* W;
  ushort_t* Wt;
  int N;
  if (bid < 1024)      { W = Wq;  Wt = WqT;  N = 2048; }
  else if (bid < 1536) { W = Wkv; Wt = WkvT; N = 1024; bid -= 1024; }
  else                 { W = Wo;  Wt = WoT;  N = 2048; bid -= 1536; }
  const int K = 2048;
  int nbx = N >> 6;
  int bx = bid % nbx, by = bid / nbx;
  int r0 = by << 6, c0 = bx << 6;
#pragma unroll
  for (int p = 0; p < 2; p++) {
    int id = p * 256 + tid;
    int r = id >> 3, cs = id & 7;
    const float* src = W + (size_t)(r0 + r) * N + c0 + cs * 8;
    f32x4 a = *(const f32x4*)(src);
    f32x4 b = *(const f32x4*)(src + 4);
    u16x8 v = {f2b(a[0]), f2b(a[1]), f2b(a[2]), f2b(a[3]),
               f2b(b[0]), f2b(b[1]), f2b(b[2]), f2b(b[3])};
    *(u16x8*)&tile[r][cs * 8] = v;
  }
  __syncthreads();
#pragma unroll
  for (int p = 0; p < 2; p++) {
    int id = p * 256 + tid;
    int oc = id >> 3, ocs = id & 7;
    u16x8 v;
#pragma unroll
    for (int j = 0; j < 8; j++) v[j] = tile[ocs * 8 + j][oc];
    *(u16x8*)(Wt + (size_t)(c0 + oc) * K + r0 + ocs * 8) = v;
  }
}

// ---------------- Merged Q+KV GEMM: one dispatch, block-uniform branch ---------
// 128x128 tile, 4 waves — the measured optimum for this 2-barrier structure
// (round 14: 136 us, ~758 TF ~ m97-structure ceiling; 256^2 tile and LDS
// swizzle both regressed, rounds 15/16). V stored kappa-permuted (swap
// bit2<->bit3 of within-tile key index) to match k_attn's exchange-free PV key
// order. Q stored PRE-SCALED by 0.125*log2(e) so k_attn's exp is exp2(sa).
__launch_bounds__(256)
__global__ void k_gemm_qkv(const ushort_t* __restrict__ A,
                           const ushort_t* __restrict__ BtQ,
                           const ushort_t* __restrict__ BtKV, int M,
                           ushort_t* __restrict__ qout, ushort_t* __restrict__ kout,
                           ushort_t* __restrict__ vout,
                           const float* __restrict__ cosT,
                           const float* __restrict__ sinT) {
  __shared__ __align__(16) ushort_t lds[2][2][128 * 32];  // [buf][A/B][row*32]
  const int tid = threadIdx.x;
  const int wave = tid >> 6, lane = tid & 63;
  const int l31 = lane & 31, hf = lane >> 5;
  const int K = 2048;
  const int bid = (int)blockIdx.x;
  const int blk = (bid & 7) * (int)(gridDim.x >> 3) + (bid >> 3);
  const int nQ = (M >> 7) << 4;
  const bool isQ = blk < nQ;
  int sub = isQ ? blk : blk - nQ;
  const int nTn = isQ ? 16 : 8;
  const ushort_t* Bt = isQ ? BtQ : BtKV;
  const int st = sub >> 4, si = sub & 15;
  const int nStc = nTn >> 2;
  const int stm = st / nStc, stn = st % nStc;
  const int bm = stm * 4 + (si >> 2), bn = stn * 4 + (si & 3);
  const int row0 = bm << 7, col0 = bn << 7;

  f32x16 acc[2][2] = {};

  auto stage = [&](int buf, int k0) {
#pragma unroll
    for (int side = 0; side < 2; side++) {
      const ushort_t* src = side ? Bt : A;
      int r0g = side ? col0 : row0;
#pragma unroll
      for (int i = 0; i < 2; i++) {
        int rl = wave * 32 + i * 16 + (lane >> 2);
        int cs = lane & 3;
        const ushort_t* gp = src + (size_t)(r0g + rl) * K + k0 + cs * 8;
        ushort_t* lp = &lds[buf][side][(wave * 32 + i * 16) * 32];
        gload_lds16(gp, lp);
      }
    }
  };

  stage(0, 0);
  __syncthreads();

  const int wm = wave >> 1, wn = wave & 1;
  const int nk = K >> 5;
  for (int kt = 0; kt < nk; kt++) {
    const int buf = kt & 1;
    if (kt + 1 < nk) stage(buf ^ 1, (kt + 1) << 5);
    const ushort_t* la = &lds[buf][0][0];
    const ushort_t* lb = &lds[buf][1][0];
#pragma unroll
    for (int ks = 0; ks < 2; ks++) {
      const int kc = ks * 2 + hf;
      bf16x8 af[2], bg[2];
#pragma unroll
      for (int mi = 0; mi < 2; mi++) {
        int r = wm * 64 + mi * 32 + l31;
        af[mi] = *(const bf16x8*)(la + r * 32 + kc * 8);
      }
#pragma unroll
      for (int ni = 0; ni < 2; ni++) {
        int r = wn * 64 + ni * 32 + l31;
        bg[ni] = *(const bf16x8*)(lb + r * 32 + kc * 8);
      }
#pragma unroll
      for (int mi = 0; mi < 2; mi++)
#pragma unroll
        for (int ni = 0; ni < 2; ni++)
          acc[mi][ni] = mfma32(af[mi], bg[ni], acc[mi][ni]);
    }
    __syncthreads();
  }

  // ---- epilogues (no barriers inside; branch is block-uniform) ----
  if (isQ) {  // q + RoPE, pre-scaled by SC = 0.125*log2(e)
    const float SC = 0.18033688011112042f;
    int cg = col0 + wn * 64 + l31;
#pragma unroll
    for (int mi = 0; mi < 2; mi++)
#pragma unroll
      for (int r = 0; r < 16; r++) {
        int rg = row0 + wm * 64 + mi * 32 + (r & 3) + 8 * (r >> 2) + 4 * hf;
        int t = rg & 4095;
        float c = cosT[t * 32 + l31];
        float s = sinT[t * 32 + l31];
        float lo = acc[mi][0][r], hi = acc[mi][1][r];
        qout[(size_t)rg * 2048 + cg]      = f2b((lo * c - hi * s) * SC);
        qout[(size_t)rg * 2048 + cg + 32] = f2b((hi * c + lo * s) * SC);
      }
  } else {
    int cb = col0 + wn * 64;
    if (cb < 512) {  // K half: RoPE, store [(b*8+g)][t][64]; cb 64-aligned
      int g = cb >> 6;
#pragma unroll
      for (int mi = 0; mi < 2; mi++)
#pragma unroll
        for (int r = 0; r < 16; r++) {
          int rg = row0 + wm * 64 + mi * 32 + (r & 3) + 8 * (r >> 2) + 4 * hf;
          int t = rg & 4095, b = rg >> 12;
          float c = cosT[t * 32 + l31];
          float s = sinT[t * 32 + l31];
          float lo = acc[mi][0][r], hi = acc[mi][1][r];
          size_t base = ((size_t)(b * 8 + g) * 4096 + t) * 64;
          kout[base + l31]      = f2b(lo * c - hi * s);
          kout[base + l31 + 32] = f2b(hi * c + lo * s);
        }
    } else {  // V half: [(b*8+g)][kt][64 d][32 keys], key index kappa-permuted
#pragma unroll
      for (int mi = 0; mi < 2; mi++)
#pragma unroll
        for (int ni = 0; ni < 2; ni++) {
          int vd = cb + ni * 32 + l31 - 512;
          int g = vd >> 6, d = vd & 63;
#pragma unroll
          for (int g2 = 0; g2 < 4; g2++) {
            int rg = row0 + wm * 64 + mi * 32 + 8 * g2 + 4 * hf;
            int b = rg >> 12, tl = rg & 4095;
            u16x4 pk = {f2b(acc[mi][ni][g2 * 4 + 0]), f2b(acc[mi][ni][g2 * 4 + 1]),
                        f2b(acc[mi][ni][g2 * 4 + 2]), f2b(acc[mi][ni][g2 * 4 + 3])};
            size_t base = (((size_t)(b * 8 + g) * 128 + (tl >> 5)) * 64 + d) * 32;
            int vtl = 16 * (g2 >> 1) + 8 * hf + 4 * (g2 & 1);
            *(u16x4*)(vout + base + vtl) = pk;
          }
        }
    }
  }
}

// ---------------- Final projection GEMM: C = A * WoT^T, fp32 out ----------------
__launch_bounds__(256)
__global__ void k_gemm_o(const ushort_t* __restrict__ A, const ushort_t* __restrict__ Bt,
                         int M, float* __restrict__ outf) {
  __shared__ __align__(16) ushort_t lds[2][2][128 * 32];
  const int tid = threadIdx.x;
  const int wave = tid >> 6, lane = tid & 63;
  const int l31 = lane & 31, hf = lane >> 5;
  const int K = 2048, N = 2048, nTn = 16;
  const int bid = (int)blockIdx.x;
  const int blk = (bid & 7) * (int)(gridDim.x >> 3) + (bid >> 3);
  const int st = blk >> 4, si = blk & 15;
  const int nStc = nTn >> 2;
  const int stm = st / nStc, stn = st % nStc;
  const int bm = stm * 4 + (si >> 2), bn = stn * 4 + (si & 3);
  const int row0 = bm << 7, col0 = bn << 7;

  f32x16 acc[2][2] = {};

  auto stage = [&](int buf, int k0) {
#pragma unroll
    for (int side = 0; side < 2; side++) {
      const ushort_t* src = side ? Bt : A;
      int r0g = side ? col0 : row0;
#pragma unroll
      for (int i = 0; i < 2; i++) {
        int rl = wave * 32 + i * 16 + (lane >> 2);
        int cs = lane & 3;
        const ushort_t* gp = src + (size_t)(r0g + rl) * K + k0 + cs * 8;
        ushort_t* lp = &lds[buf][side][(wave * 32 + i * 16) * 32];
        gload_lds16(gp, lp);
      }
    }
  };

  stage(0, 0);
  __syncthreads();

  const int wm = wave >> 1, wn = wave & 1;
  const int nk = K >> 5;
  for (int kt = 0; kt < nk; kt++) {
    const int buf = kt & 1;
    if (kt + 1 < nk) stage(buf ^ 1, (kt + 1) << 5);
    const ushort_t* la = &lds[buf][0][0];
    const ushort_t* lb = &lds[buf][1][0];
#pragma unroll
    for (int ks = 0; ks < 2; ks++) {
      const int kc = ks * 2 + hf;
      bf16x8 af[2], bg[2];
#pragma unroll
      for (int mi = 0; mi < 2; mi++) {
        int r = wm * 64 + mi * 32 + l31;
        af[mi] = *(const bf16x8*)(la + r * 32 + kc * 8);
      }
#pragma unroll
      for (int ni = 0; ni < 2; ni++) {
        int r = wn * 64 + ni * 32 + l31;
        bg[ni] = *(const bf16x8*)(lb + r * 32 + kc * 8);
      }
#pragma unroll
      for (int mi = 0; mi < 2; mi++)
#pragma unroll
        for (int ni = 0; ni < 2; ni++)
          acc[mi][ni] = mfma32(af[mi], bg[ni], acc[mi][ni]);
    }
    __syncthreads();
  }

#pragma unroll
  for (int mi = 0; mi < 2; mi++)
#pragma unroll
    for (int ni = 0; ni < 2; ni++) {
      int cg = col0 + wn * 64 + ni * 32 + l31;
#pragma unroll
      for (int r = 0; r < 16; r++) {
        int rg = row0 + wm * 64 + mi * 32 + (r & 3) + 8 * (r >> 2) + 4 * hf;
        outf[(size_t)rg * N + cg] = acc[mi][ni][r];
      }
    }
}

// ---------------- Flash attention, sliding window, GQA ----------------
// Block-cooperative LDS staging. permlane32_swap BANNED (rounds 1&6). Fixed-m
// softmax with m folded away (Q pre-scaled by 0.125*log2(e): p = exp2(sa)
// directly; o/l scale-invariant; masked -1e30 -> 0 exactly). kappa-permuted V
// keeps PV exchange-free. KVBLK=64: two 32-key sub-tiles per loop iteration.
// In-place output over its own q block. (Round-14 proven configuration.)
__launch_bounds__(256)
__global__ void k_attn(ushort_t* __restrict__ q, const ushort_t* __restrict__ kk,
                       const ushort_t* __restrict__ vT) {
  __shared__ __align__(16) ushort_t Kl[2][64][68];   // [buf][j*32+key][64 d +4 pad]
  __shared__ __align__(16) ushort_t Vl[2][128][36];  // [buf][j*64+d][32 keys +4 pad]
  const int tid = threadIdx.x;
  const int wave = tid >> 6, lane = tid & 63;
  const int l31 = lane & 31, hf = lane >> 5;
  // T1: XCD-chunked bijective remap (gridDim.x % 8 == 0 holds: 2048 blocks)
  const int chunk = gridDim.x >> 3;
  const int blk = ((int)blockIdx.x & 7) * chunk + ((int)blockIdx.x >> 3);
  const int bh = blk >> 5, qt4 = 31 - (blk & 31);   // long blocks first
  const int b = bh >> 5, hd = bh & 31;
  const int g = hd >> 2;
  const int qt = qt4 * 4 + wave;
  const int t0 = qt << 5;
  const float NEG = -1e30f;

  const ushort_t* qp = q + ((size_t)(b * 4096 + t0 + l31)) * 2048 + hd * 64 + hf * 8;
  bf16x8 qf[4];
#pragma unroll
  for (int ks = 0; ks < 4; ks++) qf[ks] = *(const bf16x8*)(qp + ks * 16);

  const ushort_t* kg = kk + (size_t)(b * 8 + g) * 4096 * 64;       // [t][64]
  const ushort_t* vg = vT + (size_t)(b * 8 + g) * 128 * 64 * 32;   // [kt][64][32]

  f32x16 o[2] = {};
  float l_i = 0.f;   // per-lane partial; cross-half reduced once at the end

  // common kt range for the whole block; pair-aligned (KTmax is always odd)
  const int KT0 = (qt4 >= 8) ? ((qt4 * 128 - 1023) >> 5) : 0;
  const int KT0e = KT0 & ~1;
  const int KTmax = qt4 * 4 + 3;

  // staging roles: K = 32 rows x 8 x 16B chunks; V = 64 rows x 4 x 16B chunks
  const int krow = tid >> 3, kchk = tid & 7;
  const int vrow = tid >> 2, vchk = tid & 3;

  // prologue: stage pair (KT0e, KT0e+1) into buf 0
#pragma unroll
  for (int j = 0; j < 2; j++) {
    u32x4 kv = *(const u32x4*)(kg + ((size_t)((KT0e + j) << 5) + krow) * 64 + kchk * 8);
    u32x4 vv = *(const u32x4*)(vg + (size_t)(KT0e + j) * 2048 + vrow * 32 + vchk * 8);
    *(u32x2*)&Kl[0][j * 32 + krow][kchk * 8]     = (u32x2){kv[0], kv[1]};
    *(u32x2*)&Kl[0][j * 32 + krow][kchk * 8 + 4] = (u32x2){kv[2], kv[3]};
    *(u32x2*)&Vl[0][j * 64 + vrow][vchk * 8]     = (u32x2){vv[0], vv[1]};
    *(u32x2*)&Vl[0][j * 64 + vrow][vchk * 8 + 4] = (u32x2){vv[2], vv[3]};
  }
  __syncthreads();

  for (int kt = KT0e; kt <= KTmax; kt += 2) {
    const int buf = ((kt - KT0e) >> 1) & 1;
    const bool more = (kt + 2 <= KTmax);

    // issue next-pair global loads early (latency hides under compute)
    u32x4 kv[2], vv[2];
    if (more) {
#pragma unroll
      for (int j = 0; j < 2; j++) {
        kv[j] = *(const u32x4*)(kg + ((size_t)((kt + 2 + j) << 5) + krow) * 64 + kchk * 8);
        vv[j] = *(const u32x4*)(vg + (size_t)(kt + 2 + j) * 2048 + vrow * 32 + vchk * 8);
      }
    }

#pragma unroll
    for (int j = 0; j < 2; j++) {
      const int ktj = kt + j;
      const int kb = ktj << 5;
      // dead-tile skip: fully masked for this wave (future, or left of window)
      const bool live = (ktj <= qt) && (kb > t0 - 1055);
      if (live) {
        // K fragments from LDS (8B-aligned b64 pairs, 2-way banks = free)
        bf16x8 kf[4];
#pragma unroll
        for (int ks = 0; ks < 4; ks++) {
          u32x2 a0 = *(const u32x2*)&Kl[buf][j * 32 + l31][hf * 8 + ks * 16];
          u32x2 a1 = *(const u32x2*)&Kl[buf][j * 32 + l31][hf * 8 + ks * 16 + 4];
          u32x4 w = {a0[0], a0[1], a1[0], a1[1]};
          kf[ks] = __builtin_bit_cast(bf16x8, w);
        }
        f32x16 sa = {};
        __builtin_amdgcn_s_setprio(1);
#pragma unroll
        for (int ks = 0; ks < 4; ks++) sa = mfma32(kf[ks], qf[ks], sa);
        __builtin_amdgcn_s_setprio(0);

        // V fragments from LDS (kappa-permuted columns)
        bf16x8 vf[2][2];
#pragma unroll
        for (int ks = 0; ks < 2; ks++)
#pragma unroll
          for (int mi = 0; mi < 2; mi++) {
            u32x2 a0 = *(const u32x2*)&Vl[buf][j * 64 + mi * 32 + l31][hf * 8 + ks * 16];
            u32x2 a1 = *(const u32x2*)&Vl[buf][j * 64 + mi * 32 + l31][hf * 8 + ks * 16 + 4];
            u32x4 w = {a0[0], a0[1], a1[0], a1[1]};
            vf[ks][mi] = __builtin_bit_cast(bf16x8, w);
          }

        // masking: diagonal tile (ktj == qt) and window left edge
        const bool need_mask = (ktj == qt) || (kb < t0 - 992);
        if (need_mask) {
          int base = (t0 + l31) - kb - 4 * hf;  // allowed iff 0 <= base - off < 1024
#pragma unroll
          for (int r = 0; r < 16; r++) {
            int off = (r & 3) + 8 * (r >> 2);
            sa[r] = ((unsigned)(base - off) < 1024u) ? sa[r] : NEG;
          }
        }
        // p = exp2(sa) directly (Q pre-scaled); masked -> exactly 0
        float p[16];
#pragma unroll
        for (int r = 0; r < 16; r++)
          p[r] = __builtin_amdgcn_exp2f(sa[r]);
        l_i += (((p[0] + p[1]) + (p[2] + p[3])) + ((p[4] + p[5]) + (p[6] + p[7]))) +
               (((p[8] + p[9]) + (p[10] + p[11])) + ((p[12] + p[13]) + (p[14] + p[15])));

        // pack P to bf16 pairs; feed PV directly (V columns kappa-permuted)
        uint32 u[8];
#pragma unroll
        for (int i = 0; i < 8; i++) {
          bf16x2 t2 = {(__bf16)p[2 * i], (__bf16)p[2 * i + 1]};
          u[i] = __builtin_bit_cast(uint32, t2);
        }

#pragma unroll
        for (int ks = 0; ks < 2; ks++) {
          u32x4 fr = {u[4 * ks + 0], u[4 * ks + 1], u[4 * ks + 2], u[4 * ks + 3]};
          bf16x8 pf = __builtin_bit_cast(bf16x8, fr);
          __builtin_amdgcn_s_setprio(1);
          o[0] = mfma32(vf[ks][0], pf, o[0]);
          o[1] = mfma32(vf[ks][1], pf, o[1]);
          __builtin_amdgcn_s_setprio(0);
        }
      }
    }

    // write next pair into the other buffer (vmcnt via data dep), then sync
    if (more) {
#pragma unroll
      for (int j = 0; j < 2; j++) {
        *(u32x2*)&Kl[buf ^ 1][j * 32 + krow][kchk * 8]     = (u32x2){kv[j][0], kv[j][1]};
        *(u32x2*)&Kl[buf ^ 1][j * 32 + krow][kchk * 8 + 4] = (u32x2){kv[j][2], kv[j][3]};
        *(u32x2*)&Vl[buf ^ 1][j * 64 + vrow][vchk * 8]     = (u32x2){vv[j][0], vv[j][1]};
        *(u32x2*)&Vl[buf ^ 1][j * 64 + vrow][vchk * 8 + 4] = (u32x2){vv[j][2], vv[j][3]};
      }
    }
    __syncthreads();
  }

  // single cross-half reduce of l (sum is associative across tiles/halves)
  l_i += __shfl_xor(l_i, 32, 64);
  float inv_l = 1.0f / fmaxf(l_i, 1e-30f);
  ushort_t* op = q + ((size_t)(b * 4096 + t0 + l31)) * 2048 + hd * 64;  // in-place
#pragma unroll
  for (int mi = 0; mi < 2; mi++)
#pragma unroll
    for (int g2 = 0; g2 < 4; g2++) {
      int d0 = mi * 32 + 8 * g2 + 4 * hf;
      bf16x4 pk = {(__bf16)(o[mi][g2 * 4 + 0] * inv_l), (__bf16)(o[mi][g2 * 4 + 1] * inv_l),
                   (__bf16)(o[mi][g2 * 4 + 2] * inv_l), (__bf16)(o[mi][g2 * 4 + 3] * inv_l)};
      *(bf16x4*)(op + d0) = pk;
    }
}

extern "C" void kernel_launch(void* const* d_in, const int* in_sizes, int n_in,
                              void* d_out, int out_size, void* d_ws, size_t ws_size,
                              hipStream_t stream) {
  const float* x   = (const float*)d_in[0];   // fp32 inputs per reference dtypes
  const float* Wq  = (const float*)d_in[1];
  const float* Wkv = (const float*)d_in[2];
  const float* Wo  = (const float*)d_in[3];
  float* outp = (float*)d_out;                // fp32 output per reference dtype

  const int BT = in_sizes[0] / 2048;  // 8192
  const int Bb = BT / 4096;           // 2

  // --- Scratch plan: d_out is 64 MiB fp32; its first 61 MiB host all scratch
  // that is dead before the final GEMM fully overwrites d_out. ws = 40 MiB.
  //   d_out: x_c[0,32M) WqT[32M,40M) WkvT[40M,44M) kbuf[44M,52M)
  //          vbuf[52M,60M) cosT[60M,60.5M) sinT[60.5M,61M)
  //   ws:    qbuf[0,32M) (attn writes in-place)  WoT[32M,40M)
  char* ob = (char*)d_out;
  const size_t MB = 1024 * 1024;
  ushort_t* x_c  = (ushort_t*)(ob);
  ushort_t* WqT  = (ushort_t*)(ob + 32 * MB);
  ushort_t* WkvT = (ushort_t*)(ob + 40 * MB);
  ushort_t* kbuf = (ushort_t*)(ob + 44 * MB);
  ushort_t* vbuf = (ushort_t*)(ob + 52 * MB);
  float*    cosT = (float*)   (ob + 60 * MB);
  float*    sinT = (float*)   (ob + 60 * MB + 512 * 1024);

  char* ws = (char*)d_ws;
  ushort_t* qbuf = (ushort_t*)(ws);
  ushort_t* WoT  = (ushort_t*)(ws + 32 * MB);

  const int nCvt = BT;  // BT*2048/(256*8)
  k_prep<<<512 + nCvt + 2560, 256, 0, stream>>>(x, x_c, nCvt, Wq, WqT, Wkv, WkvT,
                                                Wo, WoT, cosT, sinT);

  k_gemm_qkv<<<(BT / 128) * 24, 256, 0, stream>>>(
      x_c, WqT, WkvT, BT, qbuf, kbuf, vbuf, cosT, sinT);

  k_attn<<<Bb * 32 * 32, 256, 0, stream>>>(qbuf, kbuf, vbuf);

  k_gemm_o<<<(BT / 128) * 16, 256, 0, stream>>>(qbuf, WoT, BT, outp);
}